// Round 15
// baseline (35.491 us; speedup 1.0000x reference)
//
#include <hip/hip_runtime.h>

#define CIN 64
#define COUT 96
#define HW_  1024
#define PPB 8          // 8 pixels per block -> 512 blocks -> 2 blocks/CU
#define NTHR 256
#define NITER 5
#define NMF_EPS 1e-20f

// Round-15: round-14 structure halved. 2 blocks/CU gives two independent
// barrier domains per CU (barrier drain of one block overlaps the other's
// compute). Register rule from rounds 8-13 still honored: per-thread W
// storage is 48 floats (j-half), total live set ~80 floats, no spill.
__global__ __launch_bounds__(NTHR) void nmf_kernel(
    const float* __restrict__ x,
    const float* __restrict__ w,
    const float* __restrict__ h0,
    float* __restrict__ out)
{
    __shared__ float  Wr[CIN][COUT];       // [i][j] 24KB; stage-2 stride-1 b32, 2-way free
    __shared__ float  Hst[COUT][12];       // [j][p] 4.5KB; rows 48B, b128-aligned at p=0/4
    __shared__ float  Tsp[CIN][12];        // [i][p] 3KB
    __shared__ float  Dpart[2][CIN][12];   // per-half partial denoms, 6KB
    __shared__ float4 Par[4];              // per-wave normalize partials

    const int t = threadIdx.x;
    const int tile = blockIdx.x;
    const int b = tile >> 7;               // 4 batches * 128 tiles
    const int hw0 = (tile & 127) << 3;     // 8 px per tile

    // stage-1 identity: (i-row, j-half, pixel-quad); bits 6,7 wave-uniform
    const int i1 = t & 63;
    const int half = (t >> 6) & 1;
    const int pq4 = ((t >> 7) & 1) << 2;   // 0 or 4
    const int jbase = half * 48;
    // stage-2 identity: (j-lane, pixel-quad); waves (2k,2k+1) pair on quad k
    const int jr = t & 127;                // active if < 96
    const int wv = t >> 6;                 // wave id 0..3
    const bool act = (jr < COUT);
    const int jrc = act ? jr : 0;

    // ---- one-time staging ----
    for (int k = t; k < CIN * COUT; k += NTHR)     // Wr <- w (coalesced)
        ((float*)Wr)[k] = w[k];
    for (int k = t; k < COUT * PPB; k += NTHR) {   // h init, [j][p]
        const int j = k >> 3;
        const int p = k & 7;
        Hst[j][p] = h0[j];
    }

    // ---- one-time: W half-row -> wreg[48] (registers; promotable) ----
    float wreg[48];
    #pragma unroll
    for (int jj = 0; jj < 48; jj += 4) {
        const float4 v = *(const float4*)&w[i1 * COUT + jbase + jj];
        wreg[jj] = v.x; wreg[jj + 1] = v.y; wreg[jj + 2] = v.z; wreg[jj + 3] = v.w;
    }

    // x for this thread's 4 pixels (contiguous hw -> one float4)
    const float4 xv = *(const float4*)&x[((size_t)b * CIN + i1) * HW_ + hw0 + pq4];

    __syncthreads();

    #pragma unroll 1
    for (int it = 0; it < NITER; ++it) {
        // ---- stage 1: partial denom over this j-half, 4 pixels ----
        float a0 = 0.f, a1 = 0.f, a2 = 0.f, a3 = 0.f;
        #pragma unroll
        for (int jj = 0; jj < 48; ++jj) {
            const float4 hv = *(const float4*)&Hst[jbase + jj][pq4];  // uniform-addr b128 bcast
            const float wj = wreg[jj];
            a0 += wj * hv.x; a1 += wj * hv.y; a2 += wj * hv.z; a3 += wj * hv.w;
        }
        *(float4*)&Dpart[half][i1][pq4] = make_float4(a0, a1, a2, a3);
        __syncthreads();   // barrier 1: Dpart ready

        // ---- combine halves, divide, write Tsp[i][p] ----
        if (half == 0) {
            const float4 o = *(const float4*)&Dpart[1][i1][pq4];
            float4 tw;
            tw.x = xv.x / ((a0 + o.x) + NMF_EPS);
            tw.y = xv.y / ((a1 + o.y) + NMF_EPS);
            tw.z = xv.z / ((a2 + o.z) + NMF_EPS);
            tw.w = xv.w / ((a3 + o.w) + NMF_EPS);
            *(float4*)&Tsp[i1][pq4] = tw;
        }
        __syncthreads();   // barrier 2: Tsp ready

        // ---- stage 2: u[px] = sum_i W[i][jr] * t[px][i], quad = wv>>1 ----
        const int q4 = (wv >> 1) << 2;
        float u0 = 0.f, u1 = 0.f, u2 = 0.f, u3 = 0.f;
        #pragma unroll
        for (int i = 0; i < CIN; ++i) {
            const float wv_ = Wr[i][jrc];                       // stride-1, 2-way free
            const float4 tv = *(const float4*)&Tsp[i][q4];      // uniform-addr b128 bcast
            u0 += wv_ * tv.x; u1 += wv_ * tv.y;
            u2 += wv_ * tv.z; u3 += wv_ * tv.w;
        }
        float hp0 = 0.f, hp1 = 0.f, hp2 = 0.f, hp3 = 0.f;
        if (act) {
            hp0 = Hst[jr][q4 + 0] * (1.f + u0);
            hp1 = Hst[jr][q4 + 1] * (1.f + u1);
            hp2 = Hst[jr][q4 + 2] * (1.f + u2);
            hp3 = Hst[jr][q4 + 3] * (1.f + u3);
        }
        // ---- normalize over j: 64-lane tree + cross-wave pair ----
        float s0 = hp0, s1 = hp1, s2 = hp2, s3 = hp3;
        #pragma unroll
        for (int d = 32; d >= 1; d >>= 1) {
            s0 += __shfl_xor(s0, d, 64);
            s1 += __shfl_xor(s1, d, 64);
            s2 += __shfl_xor(s2, d, 64);
            s3 += __shfl_xor(s3, d, 64);
        }
        if ((t & 63) == 0) Par[wv] = make_float4(s0, s1, s2, s3);
        __syncthreads();   // barrier 3: Par ready
        const float4 other = Par[wv ^ 1];
        const float inv0 = 1.f / ((s0 + other.x) + NMF_EPS);
        const float inv1 = 1.f / ((s1 + other.y) + NMF_EPS);
        const float inv2 = 1.f / ((s2 + other.z) + NMF_EPS);
        const float inv3 = 1.f / ((s3 + other.w) + NMF_EPS);
        if (act) {
            Hst[jr][q4 + 0] = hp0 * inv0;
            Hst[jr][q4 + 1] = hp1 * inv1;
            Hst[jr][q4 + 2] = hp2 * inv2;
            Hst[jr][q4 + 3] = hp3 * inv3;
        }
        __syncthreads();   // barrier 4: Hst ready for next iteration
    }

    // ---- write h -> out (B, Cout, H, W) ----
    for (int k = t; k < COUT * PPB; k += NTHR) {
        const int j = k >> 3;
        const int p = k & 7;
        out[((size_t)b * COUT + j) * HW_ + hw0 + p] = Hst[j][p];
    }
}

extern "C" void kernel_launch(void* const* d_in, const int* in_sizes, int n_in,
                              void* d_out, int out_size, void* d_ws, size_t ws_size,
                              hipStream_t stream) {
    const float* x  = (const float*)d_in[0];
    const float* w  = (const float*)d_in[1];
    const float* h0 = (const float*)d_in[2];
    float* out = (float*)d_out;
    nmf_kernel<<<512, NTHR, 0, stream>>>(x, w, h0, out);
}

// Round 16
// 27.710 us; speedup vs baseline: 1.2808x; 1.2808x over previous
//
#include <hip/hip_runtime.h>

#define CIN 64
#define COUT 96
#define HW_  1024
#define PPB 16
#define NTHR 512
#define NITER 5
#define NMF_EPS 1e-20f

// Round-16: LDS-pipe-bound analysis. Stage 2 re-identified as (j-quad, px-quad)
// on waves 0-1: per i one b128 W read (4 j) + one broadcast b128 Tsp read (4 px)
// feeds 16 FMAs. h kept in registers across iterations (16 floats); Hst in LDS
// exists only for stage-1 broadcasts (XOR-swizzled px-quad to spread banks).
// Normalize = in-wave shuffle butterfly (no Par, 3 barriers/iter).
#define UPD(P, H, U) P.x=H.x*(1.f+U.x); P.y=H.y*(1.f+U.y); P.z=H.z*(1.f+U.z); P.w=H.w*(1.f+U.w);
#define SCL(H, P)    H.x=P.x*inv.x;     H.y=P.y*inv.y;     H.z=P.z*inv.z;     H.w=P.w*inv.w;

__global__ __launch_bounds__(NTHR) void nmf_kernel(
    const float* __restrict__ x,
    const float* __restrict__ w,
    const float* __restrict__ h0,
    float* __restrict__ out)
{
    __shared__ float Wr[CIN][COUT];        // [i][j] flat copy of w, 24KB
    __shared__ float Hst[COUT][16];        // [j][px^swz(j)], 6KB; swz spreads write banks
    __shared__ float Tsp[CIN][20];         // [i][p], 5KB
    __shared__ float Dpart[2][CIN][20];    // stage-1 half partials, 10KB

    const int t = threadIdx.x;
    const int tile = blockIdx.x;
    const int b = tile >> 6;               // 4 batches * 64 tiles
    const int hw0 = (tile & 63) << 4;      // 16 px per tile

    // stage-1 identity: (i-row, j-half, px-quad)
    const int i1 = t & 63;
    const int half = (t >> 6) & 1;
    const int s1pq = (t >> 7) << 2;        // 0,4,8,12
    const int jbase = half * 48;
    // stage-2 identity (threads 0..127): (j-quad, px-quad)
    const int jq = t & 31;                 // active if < 24
    const int jqc = (jq < 24) ? jq : 23;
    const int s2pq = ((t >> 5) & 3) << 2;  // 0,4,8,12
    const int wcol = s2pq ^ ((jqc & 3) << 2);   // swizzled px-quad col for Hst
    const bool s2on = (t < 128);

    // ---- staging: Wr flat float4 copy (3 iters/thread) ----
    for (int k = t; k < (CIN * COUT) / 4; k += NTHR)
        ((float4*)Wr)[k] = ((const float4*)w)[k];

    // ---- stage-1 W half-row in registers ----
    float wreg[48];
    #pragma unroll
    for (int jj = 0; jj < 48; jj += 4) {
        const float4 v = *(const float4*)&w[i1 * COUT + jbase + jj];
        wreg[jj] = v.x; wreg[jj+1] = v.y; wreg[jj+2] = v.z; wreg[jj+3] = v.w;
    }

    // ---- h in registers (4 j x 4 px) + initial Hst fill ----
    float4 hj0, hj1, hj2, hj3;
    if (s2on) {
        const float4 h4 = *(const float4*)&h0[jqc * 4];
        hj0 = make_float4(h4.x, h4.x, h4.x, h4.x);
        hj1 = make_float4(h4.y, h4.y, h4.y, h4.y);
        hj2 = make_float4(h4.z, h4.z, h4.z, h4.z);
        hj3 = make_float4(h4.w, h4.w, h4.w, h4.w);
        if (jq < 24) {
            *(float4*)&Hst[jq*4+0][wcol] = hj0;
            *(float4*)&Hst[jq*4+1][wcol] = hj1;
            *(float4*)&Hst[jq*4+2][wcol] = hj2;
            *(float4*)&Hst[jq*4+3][wcol] = hj3;
        }
    }

    // x for this thread's stage-1 pixel-quad
    const float4 xv = *(const float4*)&x[((size_t)b * CIN + i1) * HW_ + hw0 + s1pq];

    __syncthreads();

    #pragma unroll 1
    for (int it = 0; it < NITER; ++it) {
        // ---- stage 1: denom partials over j-half; broadcast Hst reads ----
        float a0 = 0.f, a1 = 0.f, a2 = 0.f, a3 = 0.f;
        #pragma unroll
        for (int jj = 0; jj < 48; ++jj) {
            const int j = jbase + jj;
            const int col = s1pq ^ (((j >> 2) & 3) << 2);        // compile-time swz per jj
            const float4 hv = *(const float4*)&Hst[j][col];      // uniform b128 broadcast
            const float wj = wreg[jj];
            a0 += wj * hv.x; a1 += wj * hv.y; a2 += wj * hv.z; a3 += wj * hv.w;
        }
        *(float4*)&Dpart[half][i1][s1pq] = make_float4(a0, a1, a2, a3);
        __syncthreads();   // barrier 1

        if (half == 0) {
            const float4 o = *(const float4*)&Dpart[1][i1][s1pq];
            float4 tw;
            tw.x = xv.x / ((a0 + o.x) + NMF_EPS);
            tw.y = xv.y / ((a1 + o.y) + NMF_EPS);
            tw.z = xv.z / ((a2 + o.z) + NMF_EPS);
            tw.w = xv.w / ((a3 + o.w) + NMF_EPS);
            *(float4*)&Tsp[i1][s1pq] = tw;
        }
        __syncthreads();   // barrier 2

        // ---- stage 2 (waves 0-1): u[4j][4px], h'=h(1+u), butterfly-normalize ----
        if (s2on) {
            float4 u0 = make_float4(0,0,0,0);
            float4 u1 = u0, u2 = u0, u3 = u0;
            #pragma unroll
            for (int i = 0; i < CIN; ++i) {
                const float4 wv = *(const float4*)&Wr[i][jqc * 4];   // 4 j, conflict~3-way floor
                const float4 tv = *(const float4*)&Tsp[i][s2pq];     // broadcast (2 addrs/wave)
                u0.x += wv.x*tv.x; u0.y += wv.x*tv.y; u0.z += wv.x*tv.z; u0.w += wv.x*tv.w;
                u1.x += wv.y*tv.x; u1.y += wv.y*tv.y; u1.z += wv.y*tv.z; u1.w += wv.y*tv.w;
                u2.x += wv.z*tv.x; u2.y += wv.z*tv.y; u2.z += wv.z*tv.z; u2.w += wv.z*tv.w;
                u3.x += wv.w*tv.x; u3.y += wv.w*tv.y; u3.z += wv.w*tv.z; u3.w += wv.w*tv.w;
            }
            float4 p0, p1, p2, p3;
            UPD(p0, hj0, u0) UPD(p1, hj1, u1) UPD(p2, hj2, u2) UPD(p3, hj3, u3)
            // local j-sum per px, zero for idle j-quads
            float4 s;
            s.x = (p0.x + p1.x) + (p2.x + p3.x);
            s.y = (p0.y + p1.y) + (p2.y + p3.y);
            s.z = (p0.z + p1.z) + (p2.z + p3.z);
            s.w = (p0.w + p1.w) + (p2.w + p3.w);
            if (jq >= 24) s = make_float4(0,0,0,0);
            #pragma unroll
            for (int d = 16; d >= 1; d >>= 1) {
                s.x += __shfl_xor(s.x, d, 64);
                s.y += __shfl_xor(s.y, d, 64);
                s.z += __shfl_xor(s.z, d, 64);
                s.w += __shfl_xor(s.w, d, 64);
            }
            const float4 inv = make_float4(1.f/(s.x + NMF_EPS), 1.f/(s.y + NMF_EPS),
                                           1.f/(s.z + NMF_EPS), 1.f/(s.w + NMF_EPS));
            SCL(hj0, p0) SCL(hj1, p1) SCL(hj2, p2) SCL(hj3, p3)
            if (jq < 24) {
                *(float4*)&Hst[jq*4+0][wcol] = hj0;
                *(float4*)&Hst[jq*4+1][wcol] = hj1;
                *(float4*)&Hst[jq*4+2][wcol] = hj2;
                *(float4*)&Hst[jq*4+3][wcol] = hj3;
            }
        }
        __syncthreads();   // barrier 3: Hst ready for next iteration
    }

    // ---- write h -> out (B, Cout, H, W), un-swizzling ----
    for (int k = t; k < COUT * PPB; k += NTHR) {
        const int j = k >> 4;
        const int p = k & 15;
        const int col = p ^ (((j >> 2) & 3) << 2);
        out[((size_t)b * COUT + j) * HW_ + hw0 + p] = Hst[j][col];
    }
}

extern "C" void kernel_launch(void* const* d_in, const int* in_sizes, int n_in,
                              void* d_out, int out_size, void* d_ws, size_t ws_size,
                              hipStream_t stream) {
    const float* x  = (const float*)d_in[0];
    const float* w  = (const float*)d_in[1];
    const float* h0 = (const float*)d_in[2];
    float* out = (float*)d_out;
    nmf_kernel<<<256, NTHR, 0, stream>>>(x, w, h0, out);
}